// Round 18
// baseline (987.669 us; speedup 1.0000x reference)
//
#include <hip/hip_runtime.h>
#include <math.h>

#define NTOT 262144
#define BROWS 64
#define THREADS 256
#define PITCH 132

typedef short bf16x8 __attribute__((ext_vector_type(8)));
typedef float f32x16 __attribute__((ext_vector_type(16)));

// ws u16 offsets; fragment-major layout within each region
#define O0H 0
#define O0L 8192
#define O1H 16384
#define O1L 81920
#define O2H 147456
#define O2L 212992
// byte offsets in d_ws after weights:
#define GCNT_OFF 557056
#define GLIST_OFF 557120

#define SOFTBAR() asm volatile("s_waitcnt lgkmcnt(0)\n\ts_barrier" ::: "memory")
#define WAITV(N) do{ asm volatile("s_waitcnt vmcnt(" #N ")" ::: "memory"); \
                     __builtin_amdgcn_sched_barrier(0); }while(0)
#define LOADG4(r0, r1, r2, r3, base) do{ \
    asm volatile("global_load_dwordx4 %0, %1, %2 offset:0"    : "=v"(r0) : "v"(voff), "s"(base)); \
    asm volatile("global_load_dwordx4 %0, %1, %2 offset:1024" : "=v"(r1) : "v"(voff), "s"(base)); \
    asm volatile("global_load_dwordx4 %0, %1, %2 offset:2048" : "=v"(r2) : "v"(voff), "s"(base)); \
    asm volatile("global_load_dwordx4 %0, %1, %2 offset:3072" : "=v"(r3) : "v"(voff), "s"(base)); \
}while(0)

__device__ __forceinline__ unsigned short bf16_rne(float x){
    unsigned u = __float_as_uint(x);
    return (unsigned short)((u + 0x7FFFu + ((u >> 16) & 1u)) >> 16);
}
__device__ __forceinline__ void split2(float x, unsigned short& h, unsigned short& l){
    h = bf16_rne(x);
    float xh = __uint_as_float(((unsigned)h) << 16);
    l = bf16_rne(x - xh);
}

__device__ __forceinline__ int frag_off(int n, int k, int nks){
    return ((((n >> 5) * nks + (k >> 4)) << 9) | (((k >> 3) & 1) << 8) | ((n & 31) << 3) | (k & 7));
}

__global__ void prep_weights(const float* __restrict__ W0, const float* __restrict__ W1,
                             const float* __restrict__ W2, unsigned short* __restrict__ ws){
    int i = blockIdx.x * 256 + threadIdx.x;
    float v; int oh, ol;
    if (i < 8192){
        int n = i >> 6, k = i & 63; v = W0[k*128 + n];
        int o = frag_off(n, k, 4);  oh = O0H + o; ol = O0L + o;
    } else if (i < 73728){
        int j = i - 8192; int n = j >> 7, k = j & 127; v = W1[k*512 + n];
        int o = frag_off(n, k, 8);  oh = O1H + o; ol = O1L + o;
    } else if (i < 139264){
        int j = i - 73728; int n = j >> 9, k = j & 511; v = W2[k*128 + n];
        int o = frag_off(n, k, 32); oh = O2H + o; ol = O2L + o;
    } else return;
    unsigned short h, l; split2(v, h, l);
    ws[oh] = h; ws[ol] = l;
}

__device__ __forceinline__ void epilogue_row(const float* __restrict__ h, float r0v, float r1v,
        float& z0o, float& z1o, float& lseo, float& wLo, float& u0o, bool& lamo){
    float wraw[9]; float wsum = 0.0f;
    #pragma unroll
    for (int j = 0; j < 9; ++j){ wraw[j] = fabsf(h[32 + j]); wsum += wraw[j]; }
    float wL = wraw[8] / wsum;
    const bool lambert = r0v < wL;
    float u0 = lambert ? (r0v / wL) : ((r0v - wL) / (1.0f - wL));
    float U1 = lambert ? 0.5f : u0;
    U1 = fmaxf(U1, 1e-12f);
    float R  = sqrtf(-2.0f * logf(U1));
    float th = 6.28318530717958647692f * r1v;
    float ce = cosf(th), se = sinf(th);
    float es0[8], es1[8];
    float ssum0 = 0.0f, ssum1 = 0.0f, lsum0 = 0.0f, lsum1 = 0.0f;
    #pragma unroll
    for (int m = 0; m < 8; ++m){
        es0[m] = expf(h[16 + 2*m]); es1[m] = expf(h[16 + 2*m + 1]);
        ssum0 += es0[m]; ssum1 += es1[m];
        lsum0 += h[2*m]; lsum1 += h[2*m + 1];
    }
    float zg0 = (R * ce) * ssum0 + lsum0;
    float zg1 = (R * se) * ssum1 + lsum1;
    float wo0 = u0 * 2.0f - 1.0f;
    float wo1 = r1v * 2.0f - 1.0f;
    bool nonzero = !((wo0 == 0.0f) && (wo1 == 0.0f));
    bool c1 = (fabsf(wo0) > fabsf(wo1)) && nonzero;
    bool c2 = (!c1) && nonzero;
    float sa0 = (wo0 == 0.0f) ? 1.0f : wo0;
    float sa1 = (wo1 == 0.0f) ? 1.0f : wo1;
    float phi = c1 ? (0.78539816339f * wo1 / sa0)
                   : (1.57079632679f - 0.78539816339f * wo0 / sa1);
    float rr = c1 ? wo0 : (c2 ? wo1 : 0.0f);
    float zl0 = rr * cosf(phi);
    float zl1 = rr * sinf(phi);
    float z0 = lambert ? zl0 : zg0;
    float z1 = lambert ? zl1 : zg1;
    float lp[9];
    #pragma unroll
    for (int m = 0; m < 8; ++m){
        float e0 = (z0 - h[2*m])     / es0[m];
        float e1 = (z1 - h[2*m + 1]) / es1[m];
        float wm = wraw[m] / wsum;
        lp[m] = (-1.83787706640934548356f + logf(wm + 1e-5f))
                - 0.5f * (e0*e0 + e1*e1)
                - (h[16 + 2*m] + h[16 + 2*m + 1]);
    }
    float pdf = (z0*z0 + z1*z1 > 1.0f) ? 0.0f : 0.31830988618f;
    lp[8] = logf(pdf + 1e-5f) + logf(wL);
    float mx = lp[0];
    #pragma unroll
    for (int j = 1; j < 9; ++j) mx = fmaxf(mx, lp[j]);
    float s = 0.0f;
    #pragma unroll
    for (int j = 0; j < 9; ++j) s += expf(lp[j] - mx);
    z0o = z0; z1o = z1; lseo = mx + logf(s); wLo = wL; u0o = u0; lamo = lambert;
}

__device__ __forceinline__ bool flag_row(float r0v, float z0, float z1, float wL, float u0, bool lam){
    return (fabsf(r0v - wL) < 5e-3f)
        || (wL < 3e-3f) || (wL > 0.5f)
        || (fabsf(z0*z0 + z1*z1 - 1.0f) < (lam ? 0.02f : 0.2f))
        || (!lam && u0 < 3e-3f);
}

__device__ __forceinline__ f32x16 bias_init(const float* __restrict__ b, int mt, int lane, int nmax){
    f32x16 c;
    const int hq = ((lane >> 5) << 2);
    #pragma unroll
    for (int r = 0; r < 16; ++r){
        int n = mt + (r & 3) + ((r >> 2) << 3) + hq;
        c[r] = (n < nmax) ? b[n] : 0.0f;
    }
    return c;
}

__device__ __forceinline__ void write_tile(unsigned short* __restrict__ ah, unsigned short* __restrict__ al,
        int brow, int m0, int lane, const f32x16 acc, bool relu){
    const int hq = ((lane >> 5) << 2);
    #pragma unroll
    for (int q = 0; q < 4; ++q){
        ushort4 vh, vl;
        #pragma unroll
        for (int r = 0; r < 4; ++r){
            float x = acc[q*4 + r];
            if (relu) x = fmaxf(x, 0.0f);
            unsigned short hh, ll; split2(x, hh, ll);
            (&vh.x)[r] = hh; (&vl.x)[r] = ll;
        }
        const int off = brow*PITCH + m0 + q*8 + hq;
        *(ushort4*)(ah + off) = vh;
        *(ushort4*)(al + off) = vl;
    }
}

__device__ __forceinline__ void write_tile_f32t(float* __restrict__ dst,
        int brow, int m0, int lane, const f32x16 acc){
    const int hq = ((lane >> 5) << 2);
    #pragma unroll
    for (int q = 0; q < 4; ++q){
        #pragma unroll
        for (int r = 0; r < 4; ++r){
            int n = m0 + q*8 + hq + r;
            dst[n*64 + brow] = fmaxf(acc[q*4 + r], 0.0f);
        }
    }
}

// dual-row MFMA: same weight frags feed two independent 32-row accumulator chains
__device__ __forceinline__ void mfma_half2(const bf16x8* wh, const bf16x8* wl,
        const unsigned short* __restrict__ acth, const unsigned short* __restrict__ actl,
        int ks0, int brow, int lane, f32x16& accA, f32x16& accB){
    const int kl = ((lane >> 5) << 3);
    __builtin_amdgcn_s_setprio(1);
    #pragma unroll
    for (int i = 0; i < 4; ++i){
        const int k0 = (ks0 + i)*16 + kl;
        bf16x8 a0h = *(const bf16x8*)(acth + brow*PITCH + k0);
        bf16x8 a0l = *(const bf16x8*)(actl + brow*PITCH + k0);
        bf16x8 a1h = *(const bf16x8*)(acth + (brow+32)*PITCH + k0);
        bf16x8 a1l = *(const bf16x8*)(actl + (brow+32)*PITCH + k0);
        accA = __builtin_amdgcn_mfma_f32_32x32x16_bf16(wh[i], a0h, accA, 0, 0, 0);
        accB = __builtin_amdgcn_mfma_f32_32x32x16_bf16(wh[i], a1h, accB, 0, 0, 0);
        accA = __builtin_amdgcn_mfma_f32_32x32x16_bf16(wh[i], a0l, accA, 0, 0, 0);
        accB = __builtin_amdgcn_mfma_f32_32x32x16_bf16(wh[i], a1l, accB, 0, 0, 0);
        accA = __builtin_amdgcn_mfma_f32_32x32x16_bf16(wl[i], a0h, accA, 0, 0, 0);
        accB = __builtin_amdgcn_mfma_f32_32x32x16_bf16(wl[i], a1h, accB, 0, 0, 0);
    }
    __builtin_amdgcn_s_setprio(0);
}

__global__ __launch_bounds__(THREADS, 2)
void gmm_mfma(const float* __restrict__ cond, const float* __restrict__ rnd,
              const unsigned short* __restrict__ ws,
              const float* __restrict__ b0, const float* __restrict__ b1,
              const float* __restrict__ b2,
              const float* __restrict__ W3, const float* __restrict__ b3,
              const float* __restrict__ W4, const float* __restrict__ b4,
              int* __restrict__ gcnt, int* __restrict__ glist,
              float* __restrict__ out)
{
    extern __shared__ unsigned char smem[];
    unsigned short* aAh = (unsigned short*)smem;          // [64][132]
    unsigned short* aAl = aAh + 64*PITCH;
    unsigned short* aBh = aAl + 64*PITCH;                 // [64][132]
    unsigned short* aBl = aBh + 64*PITCH;                 // ends at byte 67584
    float* h2f = (float*)smem;                            // [128][64] overlays aA
    float* h3f = (float*)(smem + 32768);                  // [32][64]
    float* h4f = (float*)(smem + 40960);                  // [41][64]
    float* b1g = (float*)(smem + 67584);                  // 512 f
    float* b2g = b1g + 512;                               // 128 f

    const int tid  = threadIdx.x;
    const int lane = tid & 63;
    const int wv   = tid >> 6;       // 0..3
    const int row0 = blockIdx.x * BROWS;
    const int ct   = wv;
    const int brow = lane & 31;
    const int m0   = ct * 32;
    const int kl   = ((lane >> 5) << 3);
    const unsigned voff = (unsigned)lane * 16;

    bf16x8 whA[4], wlA[4], whB[4], wlB[4];

    // stage biases to LDS (keep counted region free of compiler vmem)
    b1g[tid] = b1[tid];
    b1g[tid + 256] = b1[tid + 256];
    if (tid < 128) b2g[tid] = b2[tid];

    // ---- L0: both row halves, shared weight frags (compiler loads) ----
    {
        f32x16 acc0a = bias_init(b0, m0, lane, 128);
        f32x16 acc0b = acc0a;
        #pragma unroll 2
        for (int ks = 0; ks < 4; ++ks){
            const int k0 = ks*16 + kl;
            const float* cp0 = cond + (size_t)(row0 + brow)*64 + k0;
            const float* cp1 = cond + (size_t)(row0 + brow + 32)*64 + k0;
            float4 ca0 = *(const float4*)cp0, cb0 = *(const float4*)(cp0 + 4);
            float4 ca1 = *(const float4*)cp1, cb1 = *(const float4*)(cp1 + 4);
            float xs0[8] = {ca0.x, ca0.y, ca0.z, ca0.w, cb0.x, cb0.y, cb0.z, cb0.w};
            float xs1[8] = {ca1.x, ca1.y, ca1.z, ca1.w, cb1.x, cb1.y, cb1.z, cb1.w};
            bf16x8 a0h, a0l, a1h, a1l;
            #pragma unroll
            for (int j = 0; j < 8; ++j){
                unsigned short hh, ll;
                split2(xs0[j], hh, ll); a0h[j] = (short)hh; a0l[j] = (short)ll;
                split2(xs1[j], hh, ll); a1h[j] = (short)hh; a1l[j] = (short)ll;
            }
            bf16x8 wh = *(const bf16x8*)(ws + O0H + (ct*4 + ks)*512 + lane*8);
            bf16x8 wl = *(const bf16x8*)(ws + O0L + (ct*4 + ks)*512 + lane*8);
            acc0a = __builtin_amdgcn_mfma_f32_32x32x16_bf16(wh, a0h, acc0a, 0, 0, 0);
            acc0b = __builtin_amdgcn_mfma_f32_32x32x16_bf16(wh, a1h, acc0b, 0, 0, 0);
            acc0a = __builtin_amdgcn_mfma_f32_32x32x16_bf16(wh, a0l, acc0a, 0, 0, 0);
            acc0b = __builtin_amdgcn_mfma_f32_32x32x16_bf16(wh, a1l, acc0b, 0, 0, 0);
            acc0a = __builtin_amdgcn_mfma_f32_32x32x16_bf16(wl, a0h, acc0a, 0, 0, 0);
            acc0b = __builtin_amdgcn_mfma_f32_32x32x16_bf16(wl, a1h, acc0b, 0, 0, 0);
        }
        write_tile(aAh, aAl, brow,      m0, lane, acc0a, true);
        write_tile(aAh, aAl, brow + 32, m0, lane, acc0b, true);
    }

    asm volatile("s_waitcnt vmcnt(0)" ::: "memory");
    __builtin_amdgcn_sched_barrier(0);
    {
        const unsigned short* p1h = ws + O1H + __builtin_amdgcn_readfirstlane(ct*4096);
        const unsigned short* p1l = ws + O1L + __builtin_amdgcn_readfirstlane(ct*4096);
        LOADG4(whA[0], whA[1], whA[2], whA[3], p1h);
        LOADG4(wlA[0], wlA[1], wlA[2], wlA[3], p1l);       // 8 in flight
    }
    SOFTBAR();   // aA + biases visible

    // ---- L1/L2 fused (4 chunks), pinned pipeline, dual-row, rolled loop ----
    f32x16 acc2a = bias_init(b2g, m0, lane, 128);
    f32x16 acc2b = acc2a;
    #pragma unroll 1
    for (int c = 0; c < 4; ++c){
        const unsigned short* b1h = ws + O1H + __builtin_amdgcn_readfirstlane((c*4 + ct)*4096);
        const unsigned short* b1l = ws + O1L + __builtin_amdgcn_readfirstlane((c*4 + ct)*4096);
        const unsigned short* c2h = ws + O2H + __builtin_amdgcn_readfirstlane((ct*32 + c*8)*512);
        const unsigned short* c2l = ws + O2L + __builtin_amdgcn_readfirstlane((ct*32 + c*8)*512);

        LOADG4(whB[0], whB[1], whB[2], whB[3], b1h + 2048);   // L1 ks4-7
        LOADG4(wlB[0], wlB[1], wlB[2], wlB[3], b1l + 2048);
        WAITV(8);                                             // L1-A ready
        f32x16 a1a = bias_init(b1g + c*128, m0, lane, 128);
        f32x16 a1b = a1a;
        mfma_half2(whA, wlA, aAh, aAl, 0, brow, lane, a1a, a1b);

        LOADG4(whA[0], whA[1], whA[2], whA[3], c2h);          // L2 ks0-3
        LOADG4(wlA[0], wlA[1], wlA[2], wlA[3], c2l);
        WAITV(8);                                             // L1-B ready
        mfma_half2(whB, wlB, aAh, aAl, 4, brow, lane, a1a, a1b);

        LOADG4(whB[0], whB[1], whB[2], whB[3], c2h + 2048);   // L2 ks4-7
        LOADG4(wlB[0], wlB[1], wlB[2], wlB[3], c2l + 2048);
        SOFTBAR();                                            // prev aB readers done
        write_tile(aBh, aBl, brow,      m0, lane, a1a, true);
        write_tile(aBh, aBl, brow + 32, m0, lane, a1b, true);
        SOFTBAR();                                            // aB visible
        WAITV(8);                                             // L2-A ready
        mfma_half2(whA, wlA, aBh, aBl, 0, brow, lane, acc2a, acc2b);

        if (c < 3){
            const unsigned short* n1h = ws + O1H + __builtin_amdgcn_readfirstlane(((c+1)*4 + ct)*4096);
            const unsigned short* n1l = ws + O1L + __builtin_amdgcn_readfirstlane(((c+1)*4 + ct)*4096);
            LOADG4(whA[0], whA[1], whA[2], whA[3], n1h);
            LOADG4(wlA[0], wlA[1], wlA[2], wlA[3], n1l);
            WAITV(8);                                         // L2-B ready, next-A in flight
        } else {
            WAITV(0);
        }
        mfma_half2(whB, wlB, aBh, aBl, 4, brow, lane, acc2a, acc2b);
    }
    SOFTBAR();   // all aA reads done; safe to overlay h2f
    write_tile_f32t(h2f, brow,      m0, lane, acc2a);
    write_tile_f32t(h2f, brow + 32, m0, lane, acc2b);
    SOFTBAR();   // h2f ready (h3f/h4f regions overlay aB: all aB reads done above)

    // ---- L3 exact fp32: row=tid&63, 4 groups of 8 cols ----
    {
        const int row = tid & 63;
        const int nb  = tid >> 6;
        float acc[8];
        #pragma unroll
        for (int c = 0; c < 8; ++c) acc[c] = b3[nb*8 + c];
        #pragma unroll 4
        for (int k = 0; k < 128; ++k){
            float a = h2f[k*64 + row];
            const float* wr = W3 + k*32 + nb*8;
            #pragma unroll
            for (int c = 0; c < 8; ++c) acc[c] = fmaf(a, wr[c], acc[c]);
        }
        SOFTBAR();
        #pragma unroll
        for (int c = 0; c < 8; ++c) h3f[(nb*8 + c)*64 + row] = fmaxf(acc[c], 0.0f);
    }
    SOFTBAR();

    // ---- L4 exact fp32: 4 groups of 11 cols (guarded) ----
    {
        const int row = tid & 63;
        const int nb  = tid >> 6;
        float acc[11];
        #pragma unroll
        for (int c = 0; c < 11; ++c){ int n = nb*11 + c; acc[c] = (n < 41) ? b4[n] : 0.0f; }
        #pragma unroll 4
        for (int k = 0; k < 32; ++k){
            float a = h3f[k*64 + row];
            const float* wr = W4 + k*41;
            #pragma unroll
            for (int c = 0; c < 11; ++c){ int n = nb*11 + c; if (n < 41) acc[c] = fmaf(a, wr[n], acc[c]); }
        }
        #pragma unroll
        for (int c = 0; c < 11; ++c){ int n = nb*11 + c; if (n < 41) h4f[n*64 + row] = acc[c]; }
    }
    SOFTBAR();

    // ---- epilogue (approx) + flag ----
    if (tid < 64){
        const int row  = tid;
        const int grow = row0 + row;
        float h[41];
        #pragma unroll
        for (int j = 0; j < 41; ++j) h[j] = h4f[j*64 + row];
        float2 rv = *(const float2*)(rnd + 2*(size_t)grow);
        float z0, z1, lse, wL, u0; bool lam;
        epilogue_row(h, rv.x, rv.y, z0, z1, lse, wL, u0, lam);
        ((float2*)out)[grow] = make_float2(z0, z1);
        out[(size_t)2*NTOT + grow] = lse;
        if (flag_row(rv.x, z0, z1, wL, u0, lam)){
            int idx = atomicAdd(gcnt, 1); glist[idx] = grow;
        }
    }
}

// deferred exact-fp32 fix-up
__global__ __launch_bounds__(512, 2)
void gmm_fix(const float* __restrict__ cond, const float* __restrict__ rnd,
             const float* __restrict__ W0, const float* __restrict__ b0,
             const float* __restrict__ W1, const float* __restrict__ b1,
             const float* __restrict__ W2, const float* __restrict__ b2,
             const float* __restrict__ W3, const float* __restrict__ b3,
             const float* __restrict__ W4, const float* __restrict__ b4,
             const int* __restrict__ gcnt, const int* __restrict__ glist,
             float* __restrict__ out)
{
    __shared__ float fb[7296];
    float* c0g = fb;            // [8][64]
    float* f0g = fb + 512;      // [8][128]
    float* f1g = fb + 1536;     // [8][512]
    float* f2g = fb + 5632;     // [8][128]
    float* f3g = fb + 6656;     // [8][32]
    float* h4g = fb + 6912;     // [8][48]
    const int tid = threadIdx.x;
    const int nflag = *gcnt;

    for (int base = blockIdx.x * 8; base < nflag; base += gridDim.x * 8){
        const int g = min(8, nflag - base);
        {
            int i = tid >> 6, k = tid & 63;
            if (i < g) c0g[i*64 + k] = cond[(size_t)glist[base + i]*64 + k];
        }
        __syncthreads();
        if (tid < 128){  // L0
            float acc[8];
            #pragma unroll
            for (int i = 0; i < 8; ++i) acc[i] = b0[tid];
            #pragma unroll 8
            for (int k = 0; k < 64; ++k){
                float w = W0[k*128 + tid];
                #pragma unroll
                for (int i = 0; i < 8; ++i) acc[i] = fmaf(c0g[i*64 + k], w, acc[i]);
            }
            for (int i = 0; i < g; ++i) f0g[i*128 + tid] = fmaxf(acc[i], 0.0f);
        }
        __syncthreads();
        {   // L1
            float acc[8];
            #pragma unroll
            for (int i = 0; i < 8; ++i) acc[i] = b1[tid];
            #pragma unroll 8
            for (int k = 0; k < 128; ++k){
                float w = W1[k*512 + tid];
                #pragma unroll
                for (int i = 0; i < 8; ++i) acc[i] = fmaf(f0g[i*128 + k], w, acc[i]);
            }
            for (int i = 0; i < g; ++i) f1g[i*512 + tid] = fmaxf(acc[i], 0.0f);
        }
        __syncthreads();
        if (tid < 128){  // L2
            float acc[8];
            #pragma unroll
            for (int i = 0; i < 8; ++i) acc[i] = b2[tid];
            #pragma unroll 8
            for (int k = 0; k < 512; ++k){
                float w = W2[k*128 + tid];
                #pragma unroll
                for (int i = 0; i < 8; ++i) acc[i] = fmaf(f1g[i*512 + k], w, acc[i]);
            }
            for (int i = 0; i < g; ++i) f2g[i*128 + tid] = fmaxf(acc[i], 0.0f);
        }
        __syncthreads();
        if (tid < 32){   // L3
            float acc[8];
            #pragma unroll
            for (int i = 0; i < 8; ++i) acc[i] = b3[tid];
            #pragma unroll 8
            for (int k = 0; k < 128; ++k){
                float w = W3[k*32 + tid];
                #pragma unroll
                for (int i = 0; i < 8; ++i) acc[i] = fmaf(f2g[i*128 + k], w, acc[i]);
            }
            for (int i = 0; i < g; ++i) f3g[i*32 + tid] = fmaxf(acc[i], 0.0f);
        }
        __syncthreads();
        if (tid < 41){   // L4
            float acc[8];
            #pragma unroll
            for (int i = 0; i < 8; ++i) acc[i] = b4[tid];
            #pragma unroll 8
            for (int k = 0; k < 32; ++k){
                float w = W4[k*41 + tid];
                #pragma unroll
                for (int i = 0; i < 8; ++i) acc[i] = fmaf(f3g[i*32 + k], w, acc[i]);
            }
            for (int i = 0; i < g; ++i) h4g[i*48 + tid] = acc[i];
        }
        __syncthreads();
        if (tid < g){
            const int grow = glist[base + tid];
            float2 rv = *(const float2*)(rnd + 2*(size_t)grow);
            float z0, z1, lse, wL, u0; bool lam;
            epilogue_row(&h4g[tid*48], rv.x, rv.y, z0, z1, lse, wL, u0, lam);
            ((float2*)out)[grow] = make_float2(z0, z1);
            out[(size_t)2*NTOT + grow] = lse;
        }
        __syncthreads();
    }
}

extern "C" void kernel_launch(void* const* d_in, const int* in_sizes, int n_in,
                              void* d_out, int out_size, void* d_ws, size_t ws_size,
                              hipStream_t stream) {
    const float* cond = (const float*)d_in[0];
    const float* rnd  = (const float*)d_in[1];
    const float* W0 = (const float*)d_in[2];  const float* b0 = (const float*)d_in[3];
    const float* W1 = (const float*)d_in[4];  const float* b1 = (const float*)d_in[5];
    const float* W2 = (const float*)d_in[6];  const float* b2 = (const float*)d_in[7];
    const float* W3 = (const float*)d_in[8];  const float* b3 = (const float*)d_in[9];
    const float* W4 = (const float*)d_in[10]; const float* b4 = (const float*)d_in[11];
    float* out = (float*)d_out;
    unsigned short* ws = (unsigned short*)d_ws;
    int* gcnt  = (int*)((char*)d_ws + GCNT_OFF);
    int* glist = (int*)((char*)d_ws + GLIST_OFF);

    (void)hipMemsetAsync(gcnt, 0, 4, stream);
    hipLaunchKernelGGL(prep_weights, dim3(544), dim3(256), 0, stream, W0, W1, W2, ws);

    hipLaunchKernelGGL(gmm_mfma, dim3(NTOT / BROWS), dim3(THREADS), 70144, stream,
                       cond, rnd, ws, b0, b1, b2, W3, b3, W4, b4, gcnt, glist, out);

    hipLaunchKernelGGL(gmm_fix, dim3(1024), dim3(512), 0, stream,
                       cond, rnd, W0, b0, W1, b1, W2, b2, W3, b3, W4, b4, gcnt, glist, out);
}

// Round 19
// 803.299 us; speedup vs baseline: 1.2295x; 1.2295x over previous
//
#include <hip/hip_runtime.h>
#include <math.h>

#define NTOT 262144
#define BROWS 32
#define THREADS 256
#define PITCH 140

typedef short bf16x8 __attribute__((ext_vector_type(8)));
typedef float f32x16 __attribute__((ext_vector_type(16)));

// ws u16 offsets; fragment-major layout within each region
#define O0H 0
#define O0L 8192
#define O1H 16384
#define O1L 81920
#define O2H 147456
#define O2L 212992
// byte offsets in d_ws after weights:
#define GCNT_OFF 557056
#define GLIST_OFF 557120

// LDS-only barrier: drain LDS ops, leave global loads in flight
#define SOFTBAR() asm volatile("s_waitcnt lgkmcnt(0)\n\ts_barrier" ::: "memory")
#define WAITV(N) do{ asm volatile("s_waitcnt vmcnt(" #N ")" ::: "memory"); \
                     __builtin_amdgcn_sched_barrier(0); }while(0)
#define LOADG4(r0, r1, r2, r3, base) do{ \
    asm volatile("global_load_dwordx4 %0, %1, %2 offset:0"    : "=v"(r0) : "v"(voff), "s"(base)); \
    asm volatile("global_load_dwordx4 %0, %1, %2 offset:1024" : "=v"(r1) : "v"(voff), "s"(base)); \
    asm volatile("global_load_dwordx4 %0, %1, %2 offset:2048" : "=v"(r2) : "v"(voff), "s"(base)); \
    asm volatile("global_load_dwordx4 %0, %1, %2 offset:3072" : "=v"(r3) : "v"(voff), "s"(base)); \
}while(0)

__device__ __forceinline__ unsigned short bf16_rne(float x){
    unsigned u = __float_as_uint(x);
    return (unsigned short)((u + 0x7FFFu + ((u >> 16) & 1u)) >> 16);
}
__device__ __forceinline__ void split2(float x, unsigned short& h, unsigned short& l){
    h = bf16_rne(x);
    float xh = __uint_as_float(((unsigned)h) << 16);
    l = bf16_rne(x - xh);
}

__device__ __forceinline__ int frag_off(int n, int k, int nks){
    return ((((n >> 5) * nks + (k >> 4)) << 9) | (((k >> 3) & 1) << 8) | ((n & 31) << 3) | (k & 7));
}

__global__ void prep_weights(const float* __restrict__ W0, const float* __restrict__ W1,
                             const float* __restrict__ W2, unsigned short* __restrict__ ws){
    int i = blockIdx.x * 256 + threadIdx.x;
    float v; int oh, ol;
    if (i < 8192){
        int n = i >> 6, k = i & 63; v = W0[k*128 + n];
        int o = frag_off(n, k, 4);  oh = O0H + o; ol = O0L + o;
    } else if (i < 73728){
        int j = i - 8192; int n = j >> 7, k = j & 127; v = W1[k*512 + n];
        int o = frag_off(n, k, 8);  oh = O1H + o; ol = O1L + o;
    } else if (i < 139264){
        int j = i - 73728; int n = j >> 9, k = j & 511; v = W2[k*128 + n];
        int o = frag_off(n, k, 32); oh = O2H + o; ol = O2L + o;
    } else return;
    unsigned short h, l; split2(v, h, l);
    ws[oh] = h; ws[ol] = l;
}

__device__ __forceinline__ void epilogue_row(const float* __restrict__ h, float r0v, float r1v,
        float& z0o, float& z1o, float& lseo, float& wLo, float& u0o, bool& lamo){
    float wraw[9]; float wsum = 0.0f;
    #pragma unroll
    for (int j = 0; j < 9; ++j){ wraw[j] = fabsf(h[32 + j]); wsum += wraw[j]; }
    float wL = wraw[8] / wsum;
    const bool lambert = r0v < wL;
    float u0 = lambert ? (r0v / wL) : ((r0v - wL) / (1.0f - wL));
    float U1 = lambert ? 0.5f : u0;
    U1 = fmaxf(U1, 1e-12f);
    float R  = sqrtf(-2.0f * logf(U1));
    float th = 6.28318530717958647692f * r1v;
    float ce = cosf(th), se = sinf(th);
    float es0[8], es1[8];
    float ssum0 = 0.0f, ssum1 = 0.0f, lsum0 = 0.0f, lsum1 = 0.0f;
    #pragma unroll
    for (int m = 0; m < 8; ++m){
        es0[m] = expf(h[16 + 2*m]); es1[m] = expf(h[16 + 2*m + 1]);
        ssum0 += es0[m]; ssum1 += es1[m];
        lsum0 += h[2*m]; lsum1 += h[2*m + 1];
    }
    float zg0 = (R * ce) * ssum0 + lsum0;
    float zg1 = (R * se) * ssum1 + lsum1;
    float wo0 = u0 * 2.0f - 1.0f;
    float wo1 = r1v * 2.0f - 1.0f;
    bool nonzero = !((wo0 == 0.0f) && (wo1 == 0.0f));
    bool c1 = (fabsf(wo0) > fabsf(wo1)) && nonzero;
    bool c2 = (!c1) && nonzero;
    float sa0 = (wo0 == 0.0f) ? 1.0f : wo0;
    float sa1 = (wo1 == 0.0f) ? 1.0f : wo1;
    float phi = c1 ? (0.78539816339f * wo1 / sa0)
                   : (1.57079632679f - 0.78539816339f * wo0 / sa1);
    float rr = c1 ? wo0 : (c2 ? wo1 : 0.0f);
    float zl0 = rr * cosf(phi);
    float zl1 = rr * sinf(phi);
    float z0 = lambert ? zl0 : zg0;
    float z1 = lambert ? zl1 : zg1;
    float lp[9];
    #pragma unroll
    for (int m = 0; m < 8; ++m){
        float e0 = (z0 - h[2*m])     / es0[m];
        float e1 = (z1 - h[2*m + 1]) / es1[m];
        float wm = wraw[m] / wsum;
        lp[m] = (-1.83787706640934548356f + logf(wm + 1e-5f))
                - 0.5f * (e0*e0 + e1*e1)
                - (h[16 + 2*m] + h[16 + 2*m + 1]);
    }
    float pdf = (z0*z0 + z1*z1 > 1.0f) ? 0.0f : 0.31830988618f;
    lp[8] = logf(pdf + 1e-5f) + logf(wL);
    float mx = lp[0];
    #pragma unroll
    for (int j = 1; j < 9; ++j) mx = fmaxf(mx, lp[j]);
    float s = 0.0f;
    #pragma unroll
    for (int j = 0; j < 9; ++j) s += expf(lp[j] - mx);
    z0o = z0; z1o = z1; lseo = mx + logf(s); wLo = wL; u0o = u0; lamo = lambert;
}

__device__ __forceinline__ bool flag_row(float r0v, float z0, float z1, float wL, float u0, bool lam){
    return (fabsf(r0v - wL) < 5e-3f)
        || (wL < 3e-3f) || (wL > 0.5f)
        || (fabsf(z0*z0 + z1*z1 - 1.0f) < (lam ? 0.02f : 0.2f))
        || (!lam && u0 < 3e-3f);
}

__device__ __forceinline__ f32x16 bias_init(const float* __restrict__ b, int mt, int lane, int nmax){
    f32x16 c;
    const int hq = ((lane >> 5) << 2);
    #pragma unroll
    for (int r = 0; r < 16; ++r){
        int n = mt + (r & 3) + ((r >> 2) << 3) + hq;
        c[r] = (n < nmax) ? b[n] : 0.0f;
    }
    return c;
}

__device__ __forceinline__ void write_tile(unsigned short* __restrict__ ah, unsigned short* __restrict__ al,
        int brow, int m0, int lane, const f32x16 acc, bool relu){
    const int hq = ((lane >> 5) << 2);
    #pragma unroll
    for (int q = 0; q < 4; ++q){
        ushort4 vh, vl;
        #pragma unroll
        for (int r = 0; r < 4; ++r){
            float x = acc[q*4 + r];
            if (relu) x = fmaxf(x, 0.0f);
            unsigned short hh, ll; split2(x, hh, ll);
            (&vh.x)[r] = hh; (&vl.x)[r] = ll;
        }
        const int off = brow*PITCH + m0 + q*8 + hq;
        *(ushort4*)(ah + off) = vh;
        *(ushort4*)(al + off) = vl;
    }
}

__device__ __forceinline__ void write_tile_f32t(float* __restrict__ dst,
        int brow, int m0, int lane, const f32x16 acc){
    const int hq = ((lane >> 5) << 2);
    #pragma unroll
    for (int q = 0; q < 4; ++q){
        #pragma unroll
        for (int r = 0; r < 4; ++r){
            int n = m0 + q*8 + hq + r;
            dst[n*32 + brow] = fmaxf(acc[q*4 + r], 0.0f);
        }
    }
}

// consume 4 k-steps from pre-loaded weight frags; setprio raises MFMA cluster priority (T5)
__device__ __forceinline__ void mfma_half(const bf16x8* wh, const bf16x8* wl,
        const unsigned short* __restrict__ acth, const unsigned short* __restrict__ actl,
        int ks0, int brow, int lane, f32x16& acc){
    const int kl = ((lane >> 5) << 3);
    __builtin_amdgcn_s_setprio(1);
    #pragma unroll
    for (int i = 0; i < 4; ++i){
        const int k0 = (ks0 + i)*16 + kl;
        bf16x8 ah = *(const bf16x8*)(acth + brow*PITCH + k0);
        bf16x8 al = *(const bf16x8*)(actl + brow*PITCH + k0);
        acc = __builtin_amdgcn_mfma_f32_32x32x16_bf16(wh[i], ah, acc, 0, 0, 0);
        acc = __builtin_amdgcn_mfma_f32_32x32x16_bf16(wh[i], al, acc, 0, 0, 0);
        acc = __builtin_amdgcn_mfma_f32_32x32x16_bf16(wl[i], ah, acc, 0, 0, 0);
    }
    __builtin_amdgcn_s_setprio(0);
}

__global__ __launch_bounds__(THREADS, 4)
void gmm_mfma(const float* __restrict__ cond, const float* __restrict__ rnd,
              const unsigned short* __restrict__ ws,
              const float* __restrict__ b0, const float* __restrict__ b1,
              const float* __restrict__ b2,
              const float* __restrict__ W3, const float* __restrict__ b3,
              const float* __restrict__ W4, const float* __restrict__ b4,
              int* __restrict__ gcnt, int* __restrict__ glist,
              float* __restrict__ out)
{
    extern __shared__ unsigned char smem[];
    // region A [0, 17920): split h0 (aAh/aAl), later h2f (16KB)
    unsigned short* aAh = (unsigned short*)smem;
    unsigned short* aAl = aAh + 32*PITCH;
    // region B [17920, 35840): split h1 chunk (aBh/aBl), later h3f+h4f
    unsigned short* aBh = (unsigned short*)(smem + 17920);
    unsigned short* aBl = aBh + 32*PITCH;
    float* h2f = (float*)smem;                    // [128 n][32 row]
    float* h3f = (float*)(smem + 17920);          // [32 n][32 row]
    float* h4f = (float*)(smem + 22016);          // [41 n][32 row]
    float* b1g = (float*)(smem + 35840);          // 512 f
    float* b2g = b1g + 512;                       // 128 f

    const int tid  = threadIdx.x;
    const int lane = tid & 63;
    const int wv   = tid >> 6;       // 0..3
    const int row0 = blockIdx.x * BROWS;
    const int ct   = wv;             // col tile 0..3
    const int brow = lane & 31;      // 32 rows/block
    const int m0   = ct * 32;
    const int kl   = ((lane >> 5) << 3);
    const unsigned voff = (unsigned)lane * 16;

    bf16x8 whA[4], wlA[4], whB[4], wlB[4];

    // stage biases to LDS
    b1g[tid] = b1[tid];
    b1g[tid + 256] = b1[tid + 256];
    if (tid < 128) b2g[tid] = b2[tid];

    // ---- L0 (compiler loads; outside counted region) ----
    {
        f32x16 acc0 = bias_init(b0, m0, lane, 128);
        #pragma unroll 2
        for (int ks = 0; ks < 4; ++ks){
            const int k0 = ks*16 + kl;
            const float* cp = cond + (size_t)(row0 + brow)*64 + k0;
            float4 ca = *(const float4*)cp;
            float4 cb = *(const float4*)(cp + 4);
            float xs[8] = {ca.x, ca.y, ca.z, ca.w, cb.x, cb.y, cb.z, cb.w};
            bf16x8 ah, al;
            #pragma unroll
            for (int j = 0; j < 8; ++j){
                unsigned short hh, ll; split2(xs[j], hh, ll);
                ah[j] = (short)hh; al[j] = (short)ll;
            }
            bf16x8 wh = *(const bf16x8*)(ws + O0H + (ct*4 + ks)*512 + lane*8);
            bf16x8 wl = *(const bf16x8*)(ws + O0L + (ct*4 + ks)*512 + lane*8);
            acc0 = __builtin_amdgcn_mfma_f32_32x32x16_bf16(wh, ah, acc0, 0, 0, 0);
            acc0 = __builtin_amdgcn_mfma_f32_32x32x16_bf16(wh, al, acc0, 0, 0, 0);
            acc0 = __builtin_amdgcn_mfma_f32_32x32x16_bf16(wl, ah, acc0, 0, 0, 0);
        }
        write_tile(aAh, aAl, brow, m0, lane, acc0, true);
    }

    asm volatile("s_waitcnt vmcnt(0)" ::: "memory");
    __builtin_amdgcn_sched_barrier(0);
    {
        const unsigned short* p1h = ws + O1H + __builtin_amdgcn_readfirstlane(ct*4096);
        const unsigned short* p1l = ws + O1L + __builtin_amdgcn_readfirstlane(ct*4096);
        LOADG4(whA[0], whA[1], whA[2], whA[3], p1h);
        LOADG4(wlA[0], wlA[1], wlA[2], wlA[3], p1l);
    }
    SOFTBAR();

    // ---- L1/L2 fused (4 chunks), pinned weight pipeline ----
    f32x16 acc2 = bias_init(b2g, m0, lane, 128);
    #pragma unroll
    for (int c = 0; c < 4; ++c){
        const unsigned short* b1h = ws + O1H + __builtin_amdgcn_readfirstlane((c*4 + ct)*4096);
        const unsigned short* b1l = ws + O1L + __builtin_amdgcn_readfirstlane((c*4 + ct)*4096);
        const unsigned short* c2h = ws + O2H + __builtin_amdgcn_readfirstlane((ct*32 + c*8)*512);
        const unsigned short* c2l = ws + O2L + __builtin_amdgcn_readfirstlane((ct*32 + c*8)*512);

        LOADG4(whB[0], whB[1], whB[2], whB[3], b1h + 2048);
        LOADG4(wlB[0], wlB[1], wlB[2], wlB[3], b1l + 2048);
        WAITV(8);
        f32x16 a1 = bias_init(b1g + c*128, m0, lane, 128);
        mfma_half(whA, wlA, aAh, aAl, 0, brow, lane, a1);

        LOADG4(whA[0], whA[1], whA[2], whA[3], c2h);
        LOADG4(wlA[0], wlA[1], wlA[2], wlA[3], c2l);
        WAITV(8);
        mfma_half(whB, wlB, aAh, aAl, 4, brow, lane, a1);

        LOADG4(whB[0], whB[1], whB[2], whB[3], c2h + 2048);
        LOADG4(wlB[0], wlB[1], wlB[2], wlB[3], c2l + 2048);
        SOFTBAR();
        write_tile(aBh, aBl, brow, m0, lane, a1, true);
        SOFTBAR();
        WAITV(8);
        mfma_half(whA, wlA, aBh, aBl, 0, brow, lane, acc2);

        if (c < 3){
            const unsigned short* n1h = ws + O1H + __builtin_amdgcn_readfirstlane(((c+1)*4 + ct)*4096);
            const unsigned short* n1l = ws + O1L + __builtin_amdgcn_readfirstlane(((c+1)*4 + ct)*4096);
            LOADG4(whA[0], whA[1], whA[2], whA[3], n1h);
            LOADG4(wlA[0], wlA[1], wlA[2], wlA[3], n1l);
            WAITV(8);
        } else {
            WAITV(0);
        }
        mfma_half(whB, wlB, aBh, aBl, 4, brow, lane, acc2);
    }
    write_tile_f32t(h2f, brow, m0, lane, acc2);
    SOFTBAR();

    // ---- L3 exact fp32: row=tid&31, 8 col-groups of 4 ----
    {
        const int row = tid & 31;
        const int nb  = tid >> 5;
        float acc[4];
        #pragma unroll
        for (int c = 0; c < 4; ++c) acc[c] = b3[nb*4 + c];
        #pragma unroll 8
        for (int k = 0; k < 128; ++k){
            float a = h2f[k*32 + row];
            const float* wr = W3 + k*32 + nb*4;
            #pragma unroll
            for (int c = 0; c < 4; ++c) acc[c] = fmaf(a, wr[c], acc[c]);
        }
        SOFTBAR();
        #pragma unroll
        for (int c = 0; c < 4; ++c) h3f[(nb*4 + c)*32 + row] = fmaxf(acc[c], 0.0f);
    }
    SOFTBAR();

    // ---- L4 exact fp32: 8 col-groups of 6 (guarded) ----
    {
        const int row = tid & 31;
        const int nb  = tid >> 5;
        float acc[6];
        #pragma unroll
        for (int c = 0; c < 6; ++c){ int n = nb*6 + c; acc[c] = (n < 41) ? b4[n] : 0.0f; }
        #pragma unroll 8
        for (int k = 0; k < 32; ++k){
            float a = h3f[k*32 + row];
            const float* wr = W4 + k*41;
            #pragma unroll
            for (int c = 0; c < 6; ++c){ int n = nb*6 + c; if (n < 41) acc[c] = fmaf(a, wr[n], acc[c]); }
        }
        #pragma unroll
        for (int c = 0; c < 6; ++c){ int n = nb*6 + c; if (n < 41) h4f[n*32 + row] = acc[c]; }
    }
    SOFTBAR();

    // ---- epilogue (approx) + flag ----
    if (tid < 32){
        const int row  = tid;
        const int grow = row0 + row;
        float h[41];
        #pragma unroll
        for (int j = 0; j < 41; ++j) h[j] = h4f[j*32 + row];
        float2 rv = *(const float2*)(rnd + 2*(size_t)grow);
        float z0, z1, lse, wL, u0; bool lam;
        epilogue_row(h, rv.x, rv.y, z0, z1, lse, wL, u0, lam);
        ((float2*)out)[grow] = make_float2(z0, z1);
        out[(size_t)2*NTOT + grow] = lse;
        if (flag_row(rv.x, z0, z1, wL, u0, lam)){
            int idx = atomicAdd(gcnt, 1); glist[idx] = grow;
        }
    }
}

// deferred exact-fp32 fix-up
__global__ __launch_bounds__(512, 2)
void gmm_fix(const float* __restrict__ cond, const float* __restrict__ rnd,
             const float* __restrict__ W0, const float* __restrict__ b0,
             const float* __restrict__ W1, const float* __restrict__ b1,
             const float* __restrict__ W2, const float* __restrict__ b2,
             const float* __restrict__ W3, const float* __restrict__ b3,
             const float* __restrict__ W4, const float* __restrict__ b4,
             const int* __restrict__ gcnt, const int* __restrict__ glist,
             float* __restrict__ out)
{
    __shared__ float fb[7296];
    float* c0g = fb;            // [8][64]
    float* f0g = fb + 512;      // [8][128]
    float* f1g = fb + 1536;     // [8][512]
    float* f2g = fb + 5632;     // [8][128]
    float* f3g = fb + 6656;     // [8][32]
    float* h4g = fb + 6912;     // [8][48]
    const int tid = threadIdx.x;
    const int nflag = *gcnt;

    for (int base = blockIdx.x * 8; base < nflag; base += gridDim.x * 8){
        const int g = min(8, nflag - base);
        {
            int i = tid >> 6, k = tid & 63;
            if (i < g) c0g[i*64 + k] = cond[(size_t)glist[base + i]*64 + k];
        }
        __syncthreads();
        if (tid < 128){  // L0
            float acc[8];
            #pragma unroll
            for (int i = 0; i < 8; ++i) acc[i] = b0[tid];
            #pragma unroll 8
            for (int k = 0; k < 64; ++k){
                float w = W0[k*128 + tid];
                #pragma unroll
                for (int i = 0; i < 8; ++i) acc[i] = fmaf(c0g[i*64 + k], w, acc[i]);
            }
            for (int i = 0; i < g; ++i) f0g[i*128 + tid] = fmaxf(acc[i], 0.0f);
        }
        __syncthreads();
        {   // L1
            float acc[8];
            #pragma unroll
            for (int i = 0; i < 8; ++i) acc[i] = b1[tid];
            #pragma unroll 8
            for (int k = 0; k < 128; ++k){
                float w = W1[k*512 + tid];
                #pragma unroll
                for (int i = 0; i < 8; ++i) acc[i] = fmaf(f0g[i*128 + k], w, acc[i]);
            }
            for (int i = 0; i < g; ++i) f1g[i*512 + tid] = fmaxf(acc[i], 0.0f);
        }
        __syncthreads();
        if (tid < 128){  // L2
            float acc[8];
            #pragma unroll
            for (int i = 0; i < 8; ++i) acc[i] = b2[tid];
            #pragma unroll 8
            for (int k = 0; k < 512; ++k){
                float w = W2[k*128 + tid];
                #pragma unroll
                for (int i = 0; i < 8; ++i) acc[i] = fmaf(f1g[i*512 + k], w, acc[i]);
            }
            for (int i = 0; i < g; ++i) f2g[i*128 + tid] = fmaxf(acc[i], 0.0f);
        }
        __syncthreads();
        if (tid < 32){   // L3
            float acc[8];
            #pragma unroll
            for (int i = 0; i < 8; ++i) acc[i] = b3[tid];
            #pragma unroll 8
            for (int k = 0; k < 128; ++k){
                float w = W3[k*32 + tid];
                #pragma unroll
                for (int i = 0; i < 8; ++i) acc[i] = fmaf(f2g[i*128 + k], w, acc[i]);
            }
            for (int i = 0; i < g; ++i) f3g[i*32 + tid] = fmaxf(acc[i], 0.0f);
        }
        __syncthreads();
        if (tid < 41){   // L4
            float acc[8];
            #pragma unroll
            for (int i = 0; i < 8; ++i) acc[i] = b4[tid];
            #pragma unroll 8
            for (int k = 0; k < 32; ++k){
                float w = W4[k*41 + tid];
                #pragma unroll
                for (int i = 0; i < 8; ++i) acc[i] = fmaf(f3g[i*32 + k], w, acc[i]);
            }
            for (int i = 0; i < g; ++i) h4g[i*48 + tid] = acc[i];
        }
        __syncthreads();
        if (tid < g){
            const int grow = glist[base + tid];
            float2 rv = *(const float2*)(rnd + 2*(size_t)grow);
            float z0, z1, lse, wL, u0; bool lam;
            epilogue_row(&h4g[tid*48], rv.x, rv.y, z0, z1, lse, wL, u0, lam);
            ((float2*)out)[grow] = make_float2(z0, z1);
            out[(size_t)2*NTOT + grow] = lse;
        }
        __syncthreads();
    }
}

extern "C" void kernel_launch(void* const* d_in, const int* in_sizes, int n_in,
                              void* d_out, int out_size, void* d_ws, size_t ws_size,
                              hipStream_t stream) {
    const float* cond = (const float*)d_in[0];
    const float* rnd  = (const float*)d_in[1];
    const float* W0 = (const float*)d_in[2];  const float* b0 = (const float*)d_in[3];
    const float* W1 = (const float*)d_in[4];  const float* b1 = (const float*)d_in[5];
    const float* W2 = (const float*)d_in[6];  const float* b2 = (const float*)d_in[7];
    const float* W3 = (const float*)d_in[8];  const float* b3 = (const float*)d_in[9];
    const float* W4 = (const float*)d_in[10]; const float* b4 = (const float*)d_in[11];
    float* out = (float*)d_out;
    unsigned short* ws = (unsigned short*)d_ws;
    int* gcnt  = (int*)((char*)d_ws + GCNT_OFF);
    int* glist = (int*)((char*)d_ws + GLIST_OFF);

    (void)hipMemsetAsync(gcnt, 0, 4, stream);
    hipLaunchKernelGGL(prep_weights, dim3(544), dim3(256), 0, stream, W0, W1, W2, ws);

    hipLaunchKernelGGL(gmm_mfma, dim3(NTOT / BROWS), dim3(THREADS), 38400, stream,
                       cond, rnd, ws, b0, b1, b2, W3, b3, W4, b4, gcnt, glist, out);

    hipLaunchKernelGGL(gmm_fix, dim3(1024), dim3(512), 0, stream,
                       cond, rnd, W0, b0, W1, b1, W2, b2, W3, b3, W4, b4, gcnt, glist, out);
}